// Round 3
// baseline (34092.001 us; speedup 1.0000x reference)
//
#include <hip/hip_runtime.h>
#include <hip/hip_cooperative_groups.h>
#include <math.h>

namespace cg = cooperative_groups;

#define BB   64      // batch
#define TT   512     // time steps
#define CIN  32
#define THF  32
#define HH   1024    // hidden
#define LL   128
#define INF  64      // CIN + THF
#define KD   1088    // INF + HH
#define KSL  68      // K-slice per q-thread (1088 / 16)
#define SROW 1092    // fallback kernel LDS pad

// ============ persistent cooperative kernel ============
// 256 wgs x 512 threads. wg (bg,cg): batches bg*8..+7, columns cg*32..+31.
// thread (q 0..15, nl 0..31): holds W[k0..k0+67][cg*32+nl] in 68 VGPRs.
__global__ __launch_bounds__(512)
void rnn_persist(const float* __restrict__ x, const float* __restrict__ tfeat,
                 const float* __restrict__ W, const float* __restrict__ bias,
                 float* __restrict__ hbuf)
{
    cg::grid_group grid = cg::this_grid();
    __shared__ float s[8 * KD];            // [8 batches][1088]: inputs(64)+h(1024)
    __shared__ float zred[8][8][32];       // [wave][batch][col]

    const int tid = threadIdx.x;
    const int bid = blockIdx.x;
    const int bg  = bid >> 5;              // 0..7
    const int cgr = bid & 31;              // 0..31
    const int nl  = tid & 31;              // 0..31 (column within tile)
    const int q   = tid >> 5;              // 0..15 (K slice)
    const int n   = cgr * 32 + nl;
    const int k0  = q * KSL;

    // one-time: W column K-slice -> registers (stays live across all 512 steps)
    float Wr[KSL];
    #pragma unroll
    for (int j = 0; j < KSL; ++j)
        Wr[j] = W[(size_t)(k0 + j) * HH + n];
    const float bn = bias[n];

    for (int t = 0; t < TT; ++t) {
        const float* hprev = hbuf + (size_t)(t & 1) * (BB * HH);
        float*       hnext = hbuf + (size_t)((t + 1) & 1) * (BB * HH);

        // ---- stage h: 8 x 1024 floats, 2048 float4 / 512 threads ----
        const float4* hp4 = reinterpret_cast<const float4*>(hprev);
        #pragma unroll
        for (int j = 0; j < 4; ++j) {
            int f = tid + 512 * j;         // 0..2047
            int b = f >> 8, c = f & 255;
            float4 v = hp4[(size_t)(bg * 8 + b) * 256 + c];
            *reinterpret_cast<float4*>(&s[b * KD + INF + 4 * c]) = v;
        }
        // ---- stage step-t inputs: 8 x 64 floats ----
        if (tid < 128) {
            int b = tid >> 4, jf = tid & 15;
            float4 v;
            if (jf < 8)
                v = *reinterpret_cast<const float4*>(&x[((size_t)(bg*8+b)*TT + t)*CIN + jf*4]);
            else
                v = *reinterpret_cast<const float4*>(&tfeat[((size_t)(bg*8+b)*TT + t)*THF + (jf-8)*4]);
            *reinterpret_cast<float4*>(&s[b * KD + jf * 4]) = v;
        }
        __syncthreads();

        // ---- compute: 8 batches x 68-long K slice against register W ----
        float acc[8];
        #pragma unroll
        for (int b8 = 0; b8 < 8; ++b8) {
            const float* srow = &s[b8 * KD + k0];
            float a0 = 0.f, a1 = 0.f, a2 = 0.f, a3 = 0.f;
            #pragma unroll
            for (int j = 0; j < KSL / 4; ++j) {
                float4 sv = *reinterpret_cast<const float4*>(srow + 4 * j);
                a0 = fmaf(sv.x, Wr[4*j+0], a0);
                a1 = fmaf(sv.y, Wr[4*j+1], a1);
                a2 = fmaf(sv.z, Wr[4*j+2], a2);
                a3 = fmaf(sv.w, Wr[4*j+3], a3);
            }
            acc[b8] = (a0 + a1) + (a2 + a3);
        }

        // ---- reduce over q: 1 in-wave shfl (q-bit0 at lane bit5) + 8 waves via LDS ----
        #pragma unroll
        for (int b8 = 0; b8 < 8; ++b8)
            acc[b8] += __shfl_xor(acc[b8], 32);

        const int w = tid >> 6;
        if ((tid & 63) < 32) {
            #pragma unroll
            for (int b8 = 0; b8 < 8; ++b8)
                zred[w][b8][nl] = acc[b8];
        }
        __syncthreads();

        if (tid < 256) {
            int b = tid >> 5, c = tid & 31;   // c == this thread's nl
            float z = bn;
            #pragma unroll
            for (int g = 0; g < 8; ++g) z += zred[g][b][c];
            hnext[(size_t)(bg*8 + b) * HH + cgr*32 + c] = tanhf(z);
        }
        __threadfence();   // make hnext visible device-wide before the barrier
        grid.sync();
    }
}

// ============ epilogue ============
__global__ __launch_bounds__(128)
void rnn_out(const float* __restrict__ h, const float* __restrict__ Wout,
             const float* __restrict__ bout, float* __restrict__ out)
{
    __shared__ float hl[HH];
    const int b = blockIdx.x, tid = threadIdx.x;
    for (int i = tid; i < HH/4; i += 128)
        *reinterpret_cast<float4*>(hl + 4*i) =
            *reinterpret_cast<const float4*>(h + (size_t)b*HH + 4*i);
    __syncthreads();
    float a0 = bout[tid], a1 = 0.f, a2 = 0.f, a3 = 0.f;
    for (int j = 0; j < HH; j += 4) {
        a0 = fmaf(hl[j+0], Wout[(size_t)(j+0)*LL + tid], a0);
        a1 = fmaf(hl[j+1], Wout[(size_t)(j+1)*LL + tid], a1);
        a2 = fmaf(hl[j+2], Wout[(size_t)(j+2)*LL + tid], a2);
        a3 = fmaf(hl[j+3], Wout[(size_t)(j+3)*LL + tid], a3);
    }
    out[(size_t)b*LL + tid] = (a0 + a1) + (a2 + a3);
}

// ============ fallback path (proven R2 kernels) ============
__global__ __launch_bounds__(256)
void transposeW(const float* __restrict__ W, float* __restrict__ Wt) {
    __shared__ float tile[32][33];
    const int nt = blockIdx.x * 32;
    const int kt = blockIdx.y * 32;
    for (int i = threadIdx.y; i < 32; i += 8)
        tile[i][threadIdx.x] = W[(size_t)(kt + i) * HH + nt + threadIdx.x];
    __syncthreads();
    for (int i = threadIdx.y; i < 32; i += 8)
        Wt[(size_t)(nt + i) * KD + kt + threadIdx.x] = tile[threadIdx.x][i];
}

__global__ __launch_bounds__(256)
void rnn_step(const float* __restrict__ x, const float* __restrict__ tfeat,
              const float* __restrict__ Wt, const float* __restrict__ bias,
              const float* __restrict__ hprev, float* __restrict__ hnext, int t)
{
    __shared__ float s[8 * SROW];
    __shared__ float zbuf[8][33];
    const int tid = threadIdx.x;
    const int bid = blockIdx.x;
    const int bg = bid >> 5, cgr = bid & 31;
    {
        const int b = tid >> 5, c = tid & 31;
        const float4* src = reinterpret_cast<const float4*>(hprev + (size_t)(bg*8 + b) * HH);
        float* dst = s + b * SROW + INF;
        #pragma unroll
        for (int i = 0; i < 8; ++i) {
            float4 v = src[c + 32*i];
            *reinterpret_cast<float4*>(dst + 4*(c + 32*i)) = v;
        }
    }
    if (tid < 128) {
        const int b = tid >> 4, j = (tid & 15) * 4;
        float4 v;
        if (j < CIN) v = *reinterpret_cast<const float4*>(x     + ((size_t)(bg*8 + b)*TT + t)*CIN + j);
        else         v = *reinterpret_cast<const float4*>(tfeat + ((size_t)(bg*8 + b)*TT + t)*THF + (j - CIN));
        *reinterpret_cast<float4*>(s + b*SROW + j) = v;
    }
    __syncthreads();
    const int w  = tid >> 6, l = tid & 63;
    const int nlb = w*8 + (l >> 3);
    const int b  = l & 7;
    const int n  = cgr*32 + nlb;
    const float* wcol = Wt + (size_t)n * KD;
    const float* srow = s + b * SROW;
    float a0 = 0.f, a1 = 0.f, a2 = 0.f, a3 = 0.f;
    #pragma unroll 2
    for (int k = 0; k < KD; k += 8) {
        float4 s0 = *reinterpret_cast<const float4*>(srow + k);
        float4 s1 = *reinterpret_cast<const float4*>(srow + k + 4);
        float4 w0 = *reinterpret_cast<const float4*>(wcol + k);
        float4 w1 = *reinterpret_cast<const float4*>(wcol + k + 4);
        a0 = fmaf(s0.x, w0.x, a0); a1 = fmaf(s0.y, w0.y, a1);
        a2 = fmaf(s0.z, w0.z, a2); a3 = fmaf(s0.w, w0.w, a3);
        a0 = fmaf(s1.x, w1.x, a0); a1 = fmaf(s1.y, w1.y, a1);
        a2 = fmaf(s1.z, w1.z, a2); a3 = fmaf(s1.w, w1.w, a3);
    }
    const float z = (a0 + a1) + (a2 + a3) + bias[n];
    zbuf[b][nlb] = tanhf(z);
    __syncthreads();
    {
        const int ob = tid >> 5, on = tid & 31;
        hnext[(size_t)(bg*8 + ob) * HH + cgr*32 + on] = zbuf[ob][on];
    }
}

__global__ __launch_bounds__(512)
void rnn_scan_kernel(const float* __restrict__ x, const float* __restrict__ tf,
                     const float* __restrict__ W, const float* __restrict__ bias,
                     const float* __restrict__ Wout, const float* __restrict__ bout,
                     float* __restrict__ out)
{
    __shared__ float s[KD];
    const int b_idx = blockIdx.x, tid = threadIdx.x;
    if (tid < CIN)      s[tid] = x[b_idx * TT * CIN + tid];
    else if (tid < INF) s[tid] = tf[b_idx * TT * THF + (tid - CIN)];
    for (int i = tid; i < HH; i += 512) s[INF + i] = 0.0f;
    __syncthreads();
    const int j0 = tid * 2;
    const float bias0 = bias[j0], bias1 = bias[j0 + 1];
    for (int t = 0; t < TT; ++t) {
        float z0 = bias0, z1 = bias1;
        #pragma unroll 8
        for (int k = 0; k < KD; ++k) {
            const float2 wv = *reinterpret_cast<const float2*>(&W[(size_t)k * HH + j0]);
            const float sv = s[k];
            z0 = fmaf(sv, wv.x, z0);
            z1 = fmaf(sv, wv.y, z1);
        }
        float nin = 0.0f;
        const int tn = t + 1;
        if (tn < TT) {
            if (tid < CIN)      nin = x[b_idx * TT * CIN + tn * CIN + tid];
            else if (tid < INF) nin = tf[b_idx * TT * THF + tn * THF + (tid - CIN)];
        }
        __syncthreads();
        s[INF + j0]     = tanhf(z0);
        s[INF + j0 + 1] = tanhf(z1);
        if (tid < INF && tn < TT) s[tid] = nin;
        __syncthreads();
    }
    for (int lll = tid; lll < LL; lll += 512) {
        float acc = bout[lll];
        for (int j = 0; j < HH; ++j) acc = fmaf(s[INF + j], Wout[(size_t)j * LL + lll], acc);
        out[(size_t)b_idx * LL + lll] = acc;
    }
}

extern "C" void kernel_launch(void* const* d_in, const int* in_sizes, int n_in,
                              void* d_out, int out_size, void* d_ws, size_t ws_size,
                              hipStream_t stream) {
    const float* x    = (const float*)d_in[0];   // [64, 512, 32]
    const float* tf   = (const float*)d_in[1];   // [64, 512, 32]
    const float* W    = (const float*)d_in[2];   // [1088, 1024]
    const float* brnn = (const float*)d_in[3];   // [1024]
    const float* Wout = (const float*)d_in[4];   // [1024, 128]
    const float* bout = (const float*)d_in[5];   // [128]
    float* out = (float*)d_out;                  // [64, 1, 128]

    float* hbuf = (float*)d_ws;                  // [2][BB][HH] ping-pong
    const size_t hbuf_elems = 2ull * BB * HH;

    if (ws_size >= hbuf_elems * sizeof(float)) {
        hipMemsetAsync(hbuf, 0, (size_t)BB * HH * sizeof(float), stream);  // h_0 = 0
        void* args[5];
        args[0] = (void*)&x;    args[1] = (void*)&tf;
        args[2] = (void*)&W;    args[3] = (void*)&brnn;
        args[4] = (void*)&hbuf;
        hipError_t e = hipLaunchCooperativeKernel(
            reinterpret_cast<void*>(rnn_persist), dim3(256), dim3(512),
            args, 0, stream);
        if (e == hipSuccess) {
            // after 512 steps, final h is in buffer parity 0
            rnn_out<<<BB, 128, 0, stream>>>(hbuf, Wout, bout, out);
            return;
        }
        (void)hipGetLastError();   // clear sticky error, fall back
    }

    // ---- fallback: multi-launch (R2) or single-wg scan (R1) ----
    const size_t need_fb = (hbuf_elems + (size_t)HH * KD) * sizeof(float);
    if (ws_size < need_fb) {
        rnn_scan_kernel<<<BB, 512, 0, stream>>>(x, tf, W, brnn, Wout, bout, out);
        return;
    }
    float* Wt = hbuf + hbuf_elems;
    hipMemsetAsync(hbuf, 0, (size_t)BB * HH * sizeof(float), stream);
    transposeW<<<dim3(HH/32, KD/32), dim3(32, 8), 0, stream>>>(W, Wt);
    for (int t = 0; t < TT; ++t) {
        rnn_step<<<256, 256, 0, stream>>>(x, tf, Wt, brnn,
                                          hbuf + (size_t)(t & 1) * BB * HH,
                                          hbuf + (size_t)((t + 1) & 1) * BB * HH,
                                          t);
    }
    rnn_out<<<BB, 128, 0, stream>>>(hbuf, Wout, bout, out);
}

// Round 4
// 29128.140 us; speedup vs baseline: 1.1704x; 1.1704x over previous
//
#include <hip/hip_runtime.h>
#include <math.h>

#define BB   64      // batch
#define TT   512     // time steps
#define CIN  32
#define THF  32
#define HH   1024    // hidden
#define LL   128
#define INF  64      // CIN + THF
#define KD   1088    // INF + HH
#define KSL  68      // K-slice per q-thread (1088 / 16)
#define SROW 1092    // fallback kernel LDS pad

// ============ persistent cooperative kernel ============
// 256 wgs x 512 threads. wg (bg,cg): batches bg*8..+7, columns cg*32..+31.
// thread (q 0..15, nl 0..31): holds W[q*68 .. +67][cg*32+nl] in 68 VGPRs.
// __launch_bounds__(512,2): 2 waves/EU -> VGPR cap 256 -> Wr stays in registers
// (R3 post-mortem: default bounds gave VGPR_Count=60 -> Wr spilled to scratch).
__global__ __launch_bounds__(512, 2)
void rnn_persist(const float* __restrict__ x, const float* __restrict__ tfeat,
                 const float* __restrict__ W, const float* __restrict__ bias,
                 float* __restrict__ hbuf,
                 unsigned* __restrict__ bar_cnt,   // [8] per-bg arrival counters
                 unsigned* __restrict__ bar_gen)   // [8] per-bg generation
{
    __shared__ float s[8 * KD];            // [8 batches][1088]: inputs(64)+h(1024)
    __shared__ float zred[8][8][32];       // [wave][batch][col]

    const int tid = threadIdx.x;
    const int bid = blockIdx.x;
    const int bg  = bid >> 5;              // 0..7
    const int cgr = bid & 31;              // 0..31
    const int nl  = tid & 31;              // 0..31 (column within tile)
    const int q   = tid >> 5;              // 0..15 (K slice)
    const int n   = cgr * 32 + nl;
    const int k0  = q * KSL;

    // one-time: W column K-slice -> registers (live across all 512 steps)
    float Wr[KSL];
    #pragma unroll
    for (int j = 0; j < KSL; ++j)
        Wr[j] = W[(size_t)(k0 + j) * HH + n];
    const float bn = bias[n];

    for (int t = 0; t < TT; ++t) {
        const float* hprev = hbuf + (size_t)(t & 1) * (BB * HH);
        float*       hnext = hbuf + (size_t)((t + 1) & 1) * (BB * HH);

        // ---- stage h: 8 x 1024 floats, 2048 float4 / 512 threads ----
        const float4* hp4 = reinterpret_cast<const float4*>(hprev);
        #pragma unroll
        for (int j = 0; j < 4; ++j) {
            int f = tid + 512 * j;         // 0..2047
            int b = f >> 8, c = f & 255;
            float4 v = hp4[(size_t)(bg * 8 + b) * 256 + c];
            *reinterpret_cast<float4*>(&s[b * KD + INF + 4 * c]) = v;
        }
        // ---- stage step-t inputs: 8 x 64 floats ----
        if (tid < 128) {
            int b = tid >> 4, jf = tid & 15;
            float4 v;
            if (jf < 8)
                v = *reinterpret_cast<const float4*>(&x[((size_t)(bg*8+b)*TT + t)*CIN + jf*4]);
            else
                v = *reinterpret_cast<const float4*>(&tfeat[((size_t)(bg*8+b)*TT + t)*THF + (jf-8)*4]);
            *reinterpret_cast<float4*>(&s[b * KD + jf * 4]) = v;
        }
        __syncthreads();

        // ---- compute: 8 batches x 68-long K slice against register W ----
        // LDS reads: 2 unique addresses per wave instr (lanes differ in column
        // only) -> broadcast, conflict-free.
        float acc[8];
        #pragma unroll
        for (int b8 = 0; b8 < 8; ++b8) {
            const float* srow = &s[b8 * KD + k0];
            float a0 = 0.f, a1 = 0.f, a2 = 0.f, a3 = 0.f;
            #pragma unroll
            for (int j = 0; j < KSL / 4; ++j) {
                float4 sv = *reinterpret_cast<const float4*>(srow + 4 * j);
                a0 = fmaf(sv.x, Wr[4*j+0], a0);
                a1 = fmaf(sv.y, Wr[4*j+1], a1);
                a2 = fmaf(sv.z, Wr[4*j+2], a2);
                a3 = fmaf(sv.w, Wr[4*j+3], a3);
            }
            acc[b8] = (a0 + a1) + (a2 + a3);
        }

        // ---- reduce over q: shfl (q-bit0 = lane bit5) + 8-wave LDS reduce ----
        #pragma unroll
        for (int b8 = 0; b8 < 8; ++b8)
            acc[b8] += __shfl_xor(acc[b8], 32);

        const int w = tid >> 6;
        if ((tid & 63) < 32) {
            #pragma unroll
            for (int b8 = 0; b8 < 8; ++b8)
                zred[w][b8][nl] = acc[b8];
        }
        __syncthreads();

        if (tid < 256) {
            int b = tid >> 5, c = tid & 31;
            float z = bn;                     // bias[n]: n == cgr*32 + (tid&31)
            #pragma unroll
            for (int g = 0; g < 8; ++g) z += zred[g][b][c];
            hnext[(size_t)(bg*8 + b) * HH + cgr*32 + c] = tanhf(z);
        }

        // ---- per-bg barrier: only the 32 wgs sharing this batch group ----
        __threadfence();                      // h writes device-visible
        __syncthreads();
        if (tid == 0) {
            const unsigned target = (unsigned)(t + 1);
            unsigned arrive = __hip_atomic_fetch_add(&bar_cnt[bg], 1u,
                                 __ATOMIC_ACQ_REL, __HIP_MEMORY_SCOPE_AGENT) + 1u;
            if (arrive == 32u * target) {
                __hip_atomic_store(&bar_gen[bg], target,
                                   __ATOMIC_RELEASE, __HIP_MEMORY_SCOPE_AGENT);
            } else {
                while (__hip_atomic_load(&bar_gen[bg],
                                         __ATOMIC_ACQUIRE, __HIP_MEMORY_SCOPE_AGENT) < target) {
                    __builtin_amdgcn_s_sleep(2);
                }
            }
        }
        __syncthreads();
    }
}

// ============ epilogue ============
__global__ __launch_bounds__(128)
void rnn_out(const float* __restrict__ h, const float* __restrict__ Wout,
             const float* __restrict__ bout, float* __restrict__ out)
{
    __shared__ float hl[HH];
    const int b = blockIdx.x, tid = threadIdx.x;
    for (int i = tid; i < HH/4; i += 128)
        *reinterpret_cast<float4*>(hl + 4*i) =
            *reinterpret_cast<const float4*>(h + (size_t)b*HH + 4*i);
    __syncthreads();
    float a0 = bout[tid], a1 = 0.f, a2 = 0.f, a3 = 0.f;
    for (int j = 0; j < HH; j += 4) {
        a0 = fmaf(hl[j+0], Wout[(size_t)(j+0)*LL + tid], a0);
        a1 = fmaf(hl[j+1], Wout[(size_t)(j+1)*LL + tid], a1);
        a2 = fmaf(hl[j+2], Wout[(size_t)(j+2)*LL + tid], a2);
        a3 = fmaf(hl[j+3], Wout[(size_t)(j+3)*LL + tid], a3);
    }
    out[(size_t)b*LL + tid] = (a0 + a1) + (a2 + a3);
}

// ============ fallback path (proven R2 kernels) ============
__global__ __launch_bounds__(256)
void transposeW(const float* __restrict__ W, float* __restrict__ Wt) {
    __shared__ float tile[32][33];
    const int nt = blockIdx.x * 32;
    const int kt = blockIdx.y * 32;
    for (int i = threadIdx.y; i < 32; i += 8)
        tile[i][threadIdx.x] = W[(size_t)(kt + i) * HH + nt + threadIdx.x];
    __syncthreads();
    for (int i = threadIdx.y; i < 32; i += 8)
        Wt[(size_t)(nt + i) * KD + kt + threadIdx.x] = tile[threadIdx.x][i];
}

__global__ __launch_bounds__(256)
void rnn_step(const float* __restrict__ x, const float* __restrict__ tfeat,
              const float* __restrict__ Wt, const float* __restrict__ bias,
              const float* __restrict__ hprev, float* __restrict__ hnext, int t)
{
    __shared__ float s[8 * SROW];
    __shared__ float zbuf[8][33];
    const int tid = threadIdx.x;
    const int bid = blockIdx.x;
    const int bg = bid >> 5, cgr = bid & 31;
    {
        const int b = tid >> 5, c = tid & 31;
        const float4* src = reinterpret_cast<const float4*>(hprev + (size_t)(bg*8 + b) * HH);
        float* dst = s + b * SROW + INF;
        #pragma unroll
        for (int i = 0; i < 8; ++i) {
            float4 v = src[c + 32*i];
            *reinterpret_cast<float4*>(dst + 4*(c + 32*i)) = v;
        }
    }
    if (tid < 128) {
        const int b = tid >> 4, j = (tid & 15) * 4;
        float4 v;
        if (j < CIN) v = *reinterpret_cast<const float4*>(x     + ((size_t)(bg*8 + b)*TT + t)*CIN + j);
        else         v = *reinterpret_cast<const float4*>(tfeat + ((size_t)(bg*8 + b)*TT + t)*THF + (j - CIN));
        *reinterpret_cast<float4*>(s + b*SROW + j) = v;
    }
    __syncthreads();
    const int w  = tid >> 6, l = tid & 63;
    const int nlb = w*8 + (l >> 3);
    const int b  = l & 7;
    const int n  = cgr*32 + nlb;
    const float* wcol = Wt + (size_t)n * KD;
    const float* srow = s + b * SROW;
    float a0 = 0.f, a1 = 0.f, a2 = 0.f, a3 = 0.f;
    #pragma unroll 2
    for (int k = 0; k < KD; k += 8) {
        float4 s0 = *reinterpret_cast<const float4*>(srow + k);
        float4 s1 = *reinterpret_cast<const float4*>(srow + k + 4);
        float4 w0 = *reinterpret_cast<const float4*>(wcol + k);
        float4 w1 = *reinterpret_cast<const float4*>(wcol + k + 4);
        a0 = fmaf(s0.x, w0.x, a0); a1 = fmaf(s0.y, w0.y, a1);
        a2 = fmaf(s0.z, w0.z, a2); a3 = fmaf(s0.w, w0.w, a3);
        a0 = fmaf(s1.x, w1.x, a0); a1 = fmaf(s1.y, w1.y, a1);
        a2 = fmaf(s1.z, w1.z, a2); a3 = fmaf(s1.w, w1.w, a3);
    }
    const float z = (a0 + a1) + (a2 + a3) + bias[n];
    zbuf[b][nlb] = tanhf(z);
    __syncthreads();
    {
        const int ob = tid >> 5, on = tid & 31;
        hnext[(size_t)(bg*8 + ob) * HH + cgr*32 + on] = zbuf[ob][on];
    }
}

__global__ __launch_bounds__(512)
void rnn_scan_kernel(const float* __restrict__ x, const float* __restrict__ tf,
                     const float* __restrict__ W, const float* __restrict__ bias,
                     const float* __restrict__ Wout, const float* __restrict__ bout,
                     float* __restrict__ out)
{
    __shared__ float s[KD];
    const int b_idx = blockIdx.x, tid = threadIdx.x;
    if (tid < CIN)      s[tid] = x[b_idx * TT * CIN + tid];
    else if (tid < INF) s[tid] = tf[b_idx * TT * THF + (tid - CIN)];
    for (int i = tid; i < HH; i += 512) s[INF + i] = 0.0f;
    __syncthreads();
    const int j0 = tid * 2;
    const float bias0 = bias[j0], bias1 = bias[j0 + 1];
    for (int t = 0; t < TT; ++t) {
        float z0 = bias0, z1 = bias1;
        #pragma unroll 8
        for (int k = 0; k < KD; ++k) {
            const float2 wv = *reinterpret_cast<const float2*>(&W[(size_t)k * HH + j0]);
            const float sv = s[k];
            z0 = fmaf(sv, wv.x, z0);
            z1 = fmaf(sv, wv.y, z1);
        }
        float nin = 0.0f;
        const int tn = t + 1;
        if (tn < TT) {
            if (tid < CIN)      nin = x[b_idx * TT * CIN + tn * CIN + tid];
            else if (tid < INF) nin = tf[b_idx * TT * THF + tn * THF + (tid - CIN)];
        }
        __syncthreads();
        s[INF + j0]     = tanhf(z0);
        s[INF + j0 + 1] = tanhf(z1);
        if (tid < INF && tn < TT) s[tid] = nin;
        __syncthreads();
    }
    for (int lll = tid; lll < LL; lll += 512) {
        float acc = bout[lll];
        for (int j = 0; j < HH; ++j) acc = fmaf(s[INF + j], Wout[(size_t)j * LL + lll], acc);
        out[(size_t)b_idx * LL + lll] = acc;
    }
}

extern "C" void kernel_launch(void* const* d_in, const int* in_sizes, int n_in,
                              void* d_out, int out_size, void* d_ws, size_t ws_size,
                              hipStream_t stream) {
    const float* x    = (const float*)d_in[0];   // [64, 512, 32]
    const float* tf   = (const float*)d_in[1];   // [64, 512, 32]
    const float* W    = (const float*)d_in[2];   // [1088, 1024]
    const float* brnn = (const float*)d_in[3];   // [1024]
    const float* Wout = (const float*)d_in[4];   // [1024, 128]
    const float* bout = (const float*)d_in[5];   // [128]
    float* out = (float*)d_out;                  // [64, 1, 128]

    float* hbuf = (float*)d_ws;                  // [2][BB][HH] ping-pong
    const size_t hbuf_elems = 2ull * BB * HH;
    unsigned* bar = (unsigned*)(hbuf + hbuf_elems);   // cnt[8], gen[8]

    if (ws_size >= hbuf_elems * sizeof(float) + 16 * sizeof(unsigned)) {
        hipMemsetAsync(hbuf, 0, (size_t)BB * HH * sizeof(float), stream);  // h_0 = 0
        hipMemsetAsync(bar, 0, 16 * sizeof(unsigned), stream);             // barriers
        unsigned* bar_cnt = bar;
        unsigned* bar_gen = bar + 8;
        void* args[7];
        args[0] = (void*)&x;       args[1] = (void*)&tf;
        args[2] = (void*)&W;       args[3] = (void*)&brnn;
        args[4] = (void*)&hbuf;    args[5] = (void*)&bar_cnt;
        args[6] = (void*)&bar_gen;
        hipError_t e = hipLaunchCooperativeKernel(
            reinterpret_cast<void*>(rnn_persist), dim3(256), dim3(512),
            args, 0, stream);
        if (e == hipSuccess) {
            rnn_out<<<BB, 128, 0, stream>>>(hbuf /* parity 0 after 512 steps */,
                                            Wout, bout, out);
            return;
        }
        (void)hipGetLastError();   // clear sticky error, fall back
    }

    // ---- fallback: multi-launch (R2) or single-wg scan (R1) ----
    const size_t need_fb = (hbuf_elems + (size_t)HH * KD) * sizeof(float);
    if (ws_size < need_fb) {
        rnn_scan_kernel<<<BB, 512, 0, stream>>>(x, tf, W, brnn, Wout, bout, out);
        return;
    }
    float* Wt = hbuf + hbuf_elems;
    hipMemsetAsync(hbuf, 0, (size_t)BB * HH * sizeof(float), stream);
    transposeW<<<dim3(HH/32, KD/32), dim3(32, 8), 0, stream>>>(W, Wt);
    for (int t = 0; t < TT; ++t) {
        rnn_step<<<256, 256, 0, stream>>>(x, tf, Wt, brnn,
                                          hbuf + (size_t)(t & 1) * BB * HH,
                                          hbuf + (size_t)((t + 1) & 1) * BB * HH,
                                          t);
    }
    rnn_out<<<BB, 128, 0, stream>>>(hbuf, Wout, bout, out);
}

// Round 5
// 4857.416 us; speedup vs baseline: 7.0185x; 5.9966x over previous
//
#include <hip/hip_runtime.h>
#include <math.h>

#define BB   64      // batch
#define TT   512     // time steps
#define CIN  32
#define THF  32
#define HH   1024    // hidden
#define LL   128
#define INF  64      // CIN + THF
#define KD   1088    // INF + HH
#define SR   1092    // LDS row stride (floats): 16B-aligned, %32==4 -> conflict-lite

// ================= per-step kernel =================
// grid 256 = 4 bg (16 batches) x 64 cg (16 cols). 512 threads.
// Two 8-col passes over a [16 x 1088] @ [1088 x 16] tile, all operands in LDS.
// thread (q 0..7, b8 0..7, nl 0..7): cols nl (within pass), batches {2b8,2b8+1},
// k-slice [q*136, q*136+136).
__global__ __launch_bounds__(512)
void rnn_step2(const float* __restrict__ x, const float* __restrict__ tfeat,
               const float* __restrict__ W,     // [KD][HH] row-major
               const float* __restrict__ bias,  // [HH]
               const float* __restrict__ hprev, // [BB][HH]
               float* __restrict__ hnext,       // [BB][HH]
               int t)
{
    __shared__ float s[16 * SR];       // [16 batches][k=0..1087] (inputs|h), padded
    __shared__ float Wl[8 * SR];       // [8 cols][k], transposed W slice, padded
    __shared__ float zr[8][16][9];     // [q][batch][col-pad]

    const int tid = threadIdx.x;
    const int bid = blockIdx.x;
    const int bg  = bid >> 6;          // 0..3
    const int cg  = bid & 63;          // 0..63
    const int b0  = bg * 16;
    const int c0  = cg * 16;

    const int q   = tid >> 6;          // 0..7
    const int b8  = (tid >> 3) & 7;    // 0..7
    const int nl  = tid & 7;           // 0..7
    const int k0  = q * 136;

    // ---- stage h_prev: 16 x 1024 floats = 4096 float4, coalesced ----
    const float4* hp4 = reinterpret_cast<const float4*>(hprev);
    #pragma unroll
    for (int i = tid; i < 4096; i += 512) {
        int b = i >> 8, c = i & 255;
        float4 v = hp4[(size_t)(b0 + b) * 256 + c];
        *reinterpret_cast<float4*>(&s[b * SR + INF + 4 * c]) = v;
    }
    // ---- stage step-t inputs: 16 x 64 floats ----
    if (tid < 256) {
        int b = tid >> 4, jf = tid & 15;
        float4 v;
        if (jf < 8)
            v = *reinterpret_cast<const float4*>(&x[((size_t)(b0 + b) * TT + t) * CIN + jf * 4]);
        else
            v = *reinterpret_cast<const float4*>(&tfeat[((size_t)(b0 + b) * TT + t) * THF + (jf - 8) * 4]);
        *reinterpret_cast<float4*>(&s[b * SR + jf * 4]) = v;
    }

    #pragma unroll
    for (int pass = 0; pass < 2; ++pass) {
        // ---- stage W slice: 8 cols (c0 + pass*8 ..) transposed into Wl[col][k] ----
        for (int i = tid; i < 2 * KD; i += 512) {
            int k = i >> 1, h4 = i & 1;
            float4 v = *reinterpret_cast<const float4*>(&W[(size_t)k * HH + c0 + pass * 8 + h4 * 4]);
            Wl[(h4 * 4 + 0) * SR + k] = v.x;
            Wl[(h4 * 4 + 1) * SR + k] = v.y;
            Wl[(h4 * 4 + 2) * SR + k] = v.z;
            Wl[(h4 * 4 + 3) * SR + k] = v.w;
        }
        __syncthreads();

        // ---- compute: 2 batches x 1 col x 136 k against LDS operands ----
        const float* wrow = &Wl[nl * SR + k0];
        const float* sA   = &s[(2 * b8)     * SR + k0];
        const float* sB   = &s[(2 * b8 + 1) * SR + k0];
        float a0 = 0.f, a1 = 0.f, b0a = 0.f, b1a = 0.f;
        #pragma unroll 4
        for (int j = 0; j < 34; ++j) {
            float4 w  = *reinterpret_cast<const float4*>(wrow + 4 * j);
            float4 va = *reinterpret_cast<const float4*>(sA   + 4 * j);
            float4 vb = *reinterpret_cast<const float4*>(sB   + 4 * j);
            a0  = fmaf(w.x, va.x, a0);  a1  = fmaf(w.y, va.y, a1);
            a0  = fmaf(w.z, va.z, a0);  a1  = fmaf(w.w, va.w, a1);
            b0a = fmaf(w.x, vb.x, b0a); b1a = fmaf(w.y, vb.y, b1a);
            b0a = fmaf(w.z, vb.z, b0a); b1a = fmaf(w.w, vb.w, b1a);
        }
        zr[q][2 * b8][nl]     = a0 + a1;
        zr[q][2 * b8 + 1][nl] = b0a + b1a;
        __syncthreads();

        // ---- reduce over q, tanh, store 8 cols of h_next ----
        if (tid < 128) {
            int b = tid >> 3, np = tid & 7;
            float z = bias[c0 + pass * 8 + np];
            #pragma unroll
            for (int g = 0; g < 8; ++g) z += zr[g][b][np];
            hnext[(size_t)(b0 + b) * HH + c0 + pass * 8 + np] = tanhf(z);
        }
        __syncthreads();   // zr & Wl free for next pass
    }
}

// ================= epilogue =================
__global__ __launch_bounds__(128)
void rnn_out(const float* __restrict__ h, const float* __restrict__ Wout,
             const float* __restrict__ bout, float* __restrict__ out)
{
    __shared__ float hl[HH];
    const int b = blockIdx.x, tid = threadIdx.x;
    for (int i = tid; i < HH / 4; i += 128)
        *reinterpret_cast<float4*>(hl + 4 * i) =
            *reinterpret_cast<const float4*>(h + (size_t)b * HH + 4 * i);
    __syncthreads();
    float a0 = bout[tid], a1 = 0.f, a2 = 0.f, a3 = 0.f;
    for (int j = 0; j < HH; j += 4) {
        a0 = fmaf(hl[j + 0], Wout[(size_t)(j + 0) * LL + tid], a0);
        a1 = fmaf(hl[j + 1], Wout[(size_t)(j + 1) * LL + tid], a1);
        a2 = fmaf(hl[j + 2], Wout[(size_t)(j + 2) * LL + tid], a2);
        a3 = fmaf(hl[j + 3], Wout[(size_t)(j + 3) * LL + tid], a3);
    }
    out[(size_t)b * LL + tid] = (a0 + a1) + (a2 + a3);
}

// ================= tiny-ws fallback (R1 kernel, proven) =================
__global__ __launch_bounds__(512)
void rnn_scan_kernel(const float* __restrict__ x, const float* __restrict__ tf,
                     const float* __restrict__ W, const float* __restrict__ bias,
                     const float* __restrict__ Wout, const float* __restrict__ bout,
                     float* __restrict__ out)
{
    __shared__ float s[KD];
    const int b_idx = blockIdx.x, tid = threadIdx.x;
    if (tid < CIN)      s[tid] = x[b_idx * TT * CIN + tid];
    else if (tid < INF) s[tid] = tf[b_idx * TT * THF + (tid - CIN)];
    for (int i = tid; i < HH; i += 512) s[INF + i] = 0.0f;
    __syncthreads();
    const int j0 = tid * 2;
    const float bias0 = bias[j0], bias1 = bias[j0 + 1];
    for (int t = 0; t < TT; ++t) {
        float z0 = bias0, z1 = bias1;
        #pragma unroll 8
        for (int k = 0; k < KD; ++k) {
            const float2 wv = *reinterpret_cast<const float2*>(&W[(size_t)k * HH + j0]);
            const float sv = s[k];
            z0 = fmaf(sv, wv.x, z0);
            z1 = fmaf(sv, wv.y, z1);
        }
        float nin = 0.0f;
        const int tn = t + 1;
        if (tn < TT) {
            if (tid < CIN)      nin = x[b_idx * TT * CIN + tn * CIN + tid];
            else if (tid < INF) nin = tf[b_idx * TT * THF + tn * THF + (tid - CIN)];
        }
        __syncthreads();
        s[INF + j0]     = tanhf(z0);
        s[INF + j0 + 1] = tanhf(z1);
        if (tid < INF && tn < TT) s[tid] = nin;
        __syncthreads();
    }
    for (int lll = tid; lll < LL; lll += 512) {
        float acc = bout[lll];
        for (int j = 0; j < HH; ++j) acc = fmaf(s[INF + j], Wout[(size_t)j * LL + lll], acc);
        out[(size_t)b_idx * LL + lll] = acc;
    }
}

extern "C" void kernel_launch(void* const* d_in, const int* in_sizes, int n_in,
                              void* d_out, int out_size, void* d_ws, size_t ws_size,
                              hipStream_t stream) {
    const float* x    = (const float*)d_in[0];   // [64, 512, 32]
    const float* tf   = (const float*)d_in[1];   // [64, 512, 32]
    const float* W    = (const float*)d_in[2];   // [1088, 1024]
    const float* brnn = (const float*)d_in[3];   // [1024]
    const float* Wout = (const float*)d_in[4];   // [1024, 128]
    const float* bout = (const float*)d_in[5];   // [128]
    float* out = (float*)d_out;                  // [64, 1, 128]

    float* hbuf = (float*)d_ws;                  // [2][BB][HH] ping-pong
    const size_t hbuf_bytes = 2ull * BB * HH * sizeof(float);

    if (ws_size < hbuf_bytes) {
        rnn_scan_kernel<<<BB, 512, 0, stream>>>(x, tf, W, brnn, Wout, bout, out);
        return;
    }

    hipMemsetAsync(hbuf, 0, (size_t)BB * HH * sizeof(float), stream);  // h_0 = 0
    for (int t = 0; t < TT; ++t) {
        rnn_step2<<<256, 512, 0, stream>>>(x, tf, W, brnn,
                                           hbuf + (size_t)(t & 1) * BB * HH,
                                           hbuf + (size_t)((t + 1) & 1) * BB * HH,
                                           t);
    }
    // after 512 steps final h is at parity 0
    rnn_out<<<BB, 128, 0, stream>>>(hbuf, Wout, bout, out);
}